// Round 1
// baseline (3816.664 us; speedup 1.0000x reference)
//
#include <hip/hip_runtime.h>
#include <math.h>

#define DIM 2048
#define HIDDEN 5632
#define NE 8
#define NTOK 2048
#define NSLOT (NTOK * 2)

typedef __attribute__((ext_vector_type(8))) short bf16x8;
typedef __attribute__((ext_vector_type(4))) float f32x4;

// ---- ws layout (bytes) ----
// [0, 65536)            scores   T*8 fp32
// [65536, 65568)        counts   8 int
// [65568, 65600)        cursor   8 int
// [65600, 65664)        offsets  8 int (padded)
// [65664, 82048)        slot_tok 4096 int
// [82048, 98432)        slot_w   4096 fp32
// [262144, ...)         hbuf     4096*5632 bf16 (46.1 MB)

__device__ __forceinline__ unsigned short f2bf(float f) {
    unsigned int u = __float_as_uint(f);
    unsigned int r = (u + 0x7fffu + ((u >> 16) & 1u)) >> 16;
    return (unsigned short)r;
}

// ---------------- gating: scores[t][e] = x[t] . gate_w[e] (fp32) -------------
__global__ __launch_bounds__(256) void gate_kernel(
    const float* __restrict__ x, const float* __restrict__ gw,
    float* __restrict__ scores) {
    int t = blockIdx.x;
    const float* xr = x + (size_t)t * DIM;
    float acc[NE];
#pragma unroll
    for (int e = 0; e < NE; e++) acc[e] = 0.f;
    for (int d = threadIdx.x; d < DIM; d += 256) {
        float xv = xr[d];
#pragma unroll
        for (int e = 0; e < NE; e++) acc[e] += xv * gw[e * DIM + d];
    }
    __shared__ float red[256];
    for (int e = 0; e < NE; e++) {
        red[threadIdx.x] = acc[e];
        __syncthreads();
        for (int s = 128; s > 0; s >>= 1) {
            if (threadIdx.x < s) red[threadIdx.x] += red[threadIdx.x + s];
            __syncthreads();
        }
        if (threadIdx.x == 0) scores[t * NE + e] = red[0];
        __syncthreads();
    }
}

// ---------------- routing: top-2 + softmax + compaction ---------------------
__global__ __launch_bounds__(256) void route_kernel(
    const float* __restrict__ scores, int* __restrict__ counts,
    int* __restrict__ cursor, int* __restrict__ offsets,
    int* __restrict__ slot_tok, float* __restrict__ slot_w) {
    int tid = threadIdx.x;
    if (tid < NE) { counts[tid] = 0; cursor[tid] = 0; }
    __syncthreads();
    // pass 1: counts
    for (int t = tid; t < NTOK; t += 256) {
        const float* s = scores + t * NE;
        int i0 = 0; float v0 = s[0];
#pragma unroll
        for (int e = 1; e < NE; e++) { float v = s[e]; if (v > v0) { v0 = v; i0 = e; } }
        int i1 = -1; float v1 = -1e30f;
#pragma unroll
        for (int e = 0; e < NE; e++) {
            if (e == i0) continue;
            float v = s[e]; if (v > v1) { v1 = v; i1 = e; }
        }
        atomicAdd(&counts[i0], 1);
        atomicAdd(&counts[i1], 1);
    }
    __syncthreads();
    if (tid == 0) {
        int acc = 0;
        for (int e = 0; e < NE; e++) { offsets[e] = acc; acc += counts[e]; }
    }
    __syncthreads();
    // pass 2: assign slots
    for (int t = tid; t < NTOK; t += 256) {
        const float* s = scores + t * NE;
        int i0 = 0; float v0 = s[0];
#pragma unroll
        for (int e = 1; e < NE; e++) { float v = s[e]; if (v > v0) { v0 = v; i0 = e; } }
        int i1 = -1; float v1 = -1e30f;
#pragma unroll
        for (int e = 0; e < NE; e++) {
            if (e == i0) continue;
            float v = s[e]; if (v > v1) { v1 = v; i1 = e; }
        }
        float e1 = expf(v1 - v0);
        float inv = 1.f / (1.f + e1);
        float p0 = inv;
        float p1 = e1 * inv;
        int s0 = offsets[i0] + atomicAdd(&cursor[i0], 1);
        slot_tok[s0] = t; slot_w[s0] = p0;
        int s1 = offsets[i1] + atomicAdd(&cursor[i1], 1);
        slot_tok[s1] = t; slot_w[s1] = p1;
    }
}

// ---------------- GEMM1: H = silu(Xg @ W1) * (Xg @ W3), bf16 out ------------
// grid: (m_tiles=32, n_tiles=88, experts=8), block 256 (4 waves)
// tile: BM=64, BN=64, BK=32; per wave: 16 rows x 64 cols (4 mfma frags x2 mats)
__global__ __launch_bounds__(256) void gemm1_kernel(
    const float* __restrict__ x, const float* __restrict__ w1,
    const float* __restrict__ w3, const int* __restrict__ counts,
    const int* __restrict__ offsets, const int* __restrict__ slot_tok,
    unsigned short* __restrict__ hbuf) {
    const int e = blockIdx.z;
    const int count = counts[e];
    const int m0 = blockIdx.x * 64;
    if (m0 >= count) return;
    const int n0 = blockIdx.y * 64;
    const int off = offsets[e];

    __shared__ __align__(16) unsigned short As[64][40];   // [m][k]
    __shared__ __align__(16) unsigned short B1s[64][40];  // [n][k]
    __shared__ __align__(16) unsigned short B3s[64][40];  // [n][k]
    __shared__ int toks[64];

    const int tid = threadIdx.x;
    if (tid < 64) {
        int m = m0 + tid;
        toks[tid] = (m < count) ? slot_tok[off + m] : -1;
    }
    __syncthreads();

    const int wave = tid >> 6;
    const int lane = tid & 63;
    const int quad = lane >> 4;
    const int l16 = lane & 15;

    f32x4 accG[4], accU[4];
#pragma unroll
    for (int j = 0; j < 4; j++) {
        accG[j] = (f32x4)(0.f);
        accU[j] = (f32x4)(0.f);
    }

    const int arow = tid >> 2;         // 0..63
    const int akcol = (tid & 3) * 8;   // 0,8,16,24
    const int bn = tid & 63;           // 0..63
    const int bk0 = (tid >> 6) * 8;    // 0,8,16,24

    const float* w1e = w1 + (size_t)e * DIM * HIDDEN;
    const float* w3e = w3 + (size_t)e * DIM * HIDDEN;
    const int atok = toks[arow];

    for (int kt = 0; kt < DIM; kt += 32) {
        __syncthreads();
        // stage A (gathered x rows, fp32 -> bf16)
        {
            bf16x8 av;
            if (atok >= 0) {
                const float* src = x + (size_t)atok * DIM + kt + akcol;
#pragma unroll
                for (int j = 0; j < 8; j++) av[j] = (short)f2bf(src[j]);
            } else {
#pragma unroll
                for (int j = 0; j < 8; j++) av[j] = 0;
            }
            *(bf16x8*)&As[arow][akcol] = av;
        }
        // stage B1/B3 transposed: Bs[n][k] = W[kt+k][n0+n]
        {
            const float* b1p = w1e + (size_t)(kt + bk0) * HIDDEN + n0 + bn;
            const float* b3p = w3e + (size_t)(kt + bk0) * HIDDEN + n0 + bn;
            bf16x8 b1v, b3v;
#pragma unroll
            for (int j = 0; j < 8; j++) {
                b1v[j] = (short)f2bf(b1p[(size_t)j * HIDDEN]);
                b3v[j] = (short)f2bf(b3p[(size_t)j * HIDDEN]);
            }
            *(bf16x8*)&B1s[bn][bk0] = b1v;
            *(bf16x8*)&B3s[bn][bk0] = b3v;
        }
        __syncthreads();
        // compute
        bf16x8 af = *(const bf16x8*)&As[wave * 16 + l16][quad * 8];
#pragma unroll
        for (int j = 0; j < 4; j++) {
            bf16x8 b1f = *(const bf16x8*)&B1s[j * 16 + l16][quad * 8];
            accG[j] = __builtin_amdgcn_mfma_f32_16x16x32_bf16(af, b1f, accG[j], 0, 0, 0);
            bf16x8 b3f = *(const bf16x8*)&B3s[j * 16 + l16][quad * 8];
            accU[j] = __builtin_amdgcn_mfma_f32_16x16x32_bf16(af, b3f, accU[j], 0, 0, 0);
        }
    }

    // epilogue: h = silu(g)*u -> bf16 hbuf
#pragma unroll
    for (int j = 0; j < 4; j++) {
#pragma unroll
        for (int r = 0; r < 4; r++) {
            int m = m0 + wave * 16 + quad * 4 + r;
            if (m < count) {
                int n = n0 + j * 16 + l16;
                float g = accG[j][r], u = accU[j][r];
                float h = (g / (1.f + expf(-g))) * u;
                hbuf[(size_t)(off + m) * HIDDEN + n] = f2bf(h);
            }
        }
    }
}

// ---------------- GEMM2: Y = H @ W2, weighted atomic scatter to out ---------
// grid: (m_tiles=32, n_tiles=32, experts=8)
__global__ __launch_bounds__(256) void gemm2_kernel(
    const unsigned short* __restrict__ hbuf, const float* __restrict__ w2,
    const int* __restrict__ counts, const int* __restrict__ offsets,
    const int* __restrict__ slot_tok, const float* __restrict__ slot_w,
    float* __restrict__ out) {
    const int e = blockIdx.z;
    const int count = counts[e];
    const int m0 = blockIdx.x * 64;
    if (m0 >= count) return;
    const int n0 = blockIdx.y * 64;
    const int off = offsets[e];

    __shared__ __align__(16) unsigned short As[64][40];  // [m][k]
    __shared__ __align__(16) unsigned short Bs[64][40];  // [n][k]
    __shared__ int toks[64];
    __shared__ float wts[64];

    const int tid = threadIdx.x;
    if (tid < 64) {
        int m = m0 + tid;
        if (m < count) {
            toks[tid] = slot_tok[off + m];
            wts[tid] = slot_w[off + m];
        } else {
            toks[tid] = -1;
            wts[tid] = 0.f;
        }
    }
    __syncthreads();

    const int wave = tid >> 6;
    const int lane = tid & 63;
    const int quad = lane >> 4;
    const int l16 = lane & 15;

    f32x4 acc[4];
#pragma unroll
    for (int j = 0; j < 4; j++) acc[j] = (f32x4)(0.f);

    const int arow = tid >> 2;
    const int akcol = (tid & 3) * 8;
    const int bn = tid & 63;
    const int bk0 = (tid >> 6) * 8;

    const float* w2e = w2 + (size_t)e * HIDDEN * DIM;
    const bool arow_valid = (m0 + arow) < count;
    const unsigned short* asrc = hbuf + (size_t)(off + m0 + arow) * HIDDEN + akcol;

    for (int kt = 0; kt < HIDDEN; kt += 32) {
        __syncthreads();
        // stage A (bf16 H rows, direct 16B copy)
        {
            bf16x8 av;
            if (arow_valid) {
                av = *(const bf16x8*)(asrc + kt);
            } else {
#pragma unroll
                for (int j = 0; j < 8; j++) av[j] = 0;
            }
            *(bf16x8*)&As[arow][akcol] = av;
        }
        // stage B transposed: Bs[n][k] = W2[kt+k][n0+n]
        {
            const float* bp = w2e + (size_t)(kt + bk0) * DIM + n0 + bn;
            bf16x8 bv;
#pragma unroll
            for (int j = 0; j < 8; j++) bv[j] = (short)f2bf(bp[(size_t)j * DIM]);
            *(bf16x8*)&Bs[bn][bk0] = bv;
        }
        __syncthreads();
        bf16x8 af = *(const bf16x8*)&As[wave * 16 + l16][quad * 8];
#pragma unroll
        for (int j = 0; j < 4; j++) {
            bf16x8 bf = *(const bf16x8*)&Bs[j * 16 + l16][quad * 8];
            acc[j] = __builtin_amdgcn_mfma_f32_16x16x32_bf16(af, bf, acc[j], 0, 0, 0);
        }
    }

    // epilogue: out[tok][n] += w * y
#pragma unroll
    for (int j = 0; j < 4; j++) {
#pragma unroll
        for (int r = 0; r < 4; r++) {
            int mrow = wave * 16 + quad * 4 + r;
            int m = m0 + mrow;
            if (m < count) {
                int tok = toks[mrow];
                float wgt = wts[mrow];
                int n = n0 + j * 16 + l16;
                atomicAdd(&out[(size_t)tok * DIM + n], wgt * acc[j][r]);
            }
        }
    }
}

extern "C" void kernel_launch(void* const* d_in, const int* in_sizes, int n_in,
                              void* d_out, int out_size, void* d_ws, size_t ws_size,
                              hipStream_t stream) {
    const float* x  = (const float*)d_in[0];
    const float* gw = (const float*)d_in[1];
    const float* w1 = (const float*)d_in[2];
    const float* w2 = (const float*)d_in[3];  // note: dict order is w1, w2, w3
    const float* w3 = (const float*)d_in[4];
    float* out = (float*)d_out;

    char* ws = (char*)d_ws;
    float* scores   = (float*)(ws + 0);
    int*   counts   = (int*)(ws + 65536);
    int*   cursor   = (int*)(ws + 65568);
    int*   offsets  = (int*)(ws + 65600);
    int*   slot_tok = (int*)(ws + 65664);
    float* slot_w   = (float*)(ws + 82048);
    unsigned short* hbuf = (unsigned short*)(ws + 262144);

    hipMemsetAsync(d_out, 0, (size_t)out_size * sizeof(float), stream);

    gate_kernel<<<NTOK, 256, 0, stream>>>(x, gw, scores);
    route_kernel<<<1, 256, 0, stream>>>(scores, counts, cursor, offsets, slot_tok, slot_w);
    gemm1_kernel<<<dim3(32, 88, 8), 256, 0, stream>>>(x, w1, w3, counts, offsets,
                                                      slot_tok, hbuf);
    gemm2_kernel<<<dim3(32, 32, 8), 256, 0, stream>>>(hbuf, w2, counts, offsets,
                                                      slot_tok, slot_w, out);
}